// Round 2
// 1029.456 us; speedup vs baseline: 1.1144x; 1.1144x over previous
//
#include <hip/hip_runtime.h>
#include <stdint.h>

// out[M,N] = x[M,K] @ W'[N,K]^T + bias[N], W' = W + SCALE*(loraB @ loraA)
// M = 16384 (B*S), N = 4096, K = 4096. SCALE = 16/16 = 1.0.
#define M_DIM 16384
#define N_DIM 4096
#define K_DIM 4096
#define LORA_SCALE 1.0f

#define BM 256
#define BN 256
#define BK 64
#define NT (K_DIM / BK)  // 64 K-tiles

typedef _Float16 half8 __attribute__((ext_vector_type(8)));
typedef float f32x4 __attribute__((ext_vector_type(4)));

// ---------------------------------------------------------------------------
// Kernel 1: x (fp32) -> f16, 8 elements/thread.
// ---------------------------------------------------------------------------
__global__ __launch_bounds__(256) void cvt_x_kernel(const float* __restrict__ x,
                                                    _Float16* __restrict__ xb) {
    size_t base = ((size_t)blockIdx.x * 256 + (size_t)threadIdx.x) * 8;
    f32x4 a = *(const f32x4*)(x + base);
    f32x4 b = *(const f32x4*)(x + base + 4);
    half8 h;
    h[0] = (_Float16)a[0]; h[1] = (_Float16)a[1];
    h[2] = (_Float16)a[2]; h[3] = (_Float16)a[3];
    h[4] = (_Float16)b[0]; h[5] = (_Float16)b[1];
    h[6] = (_Float16)b[2]; h[7] = (_Float16)b[3];
    *(half8*)(xb + base) = h;
}

// ---------------------------------------------------------------------------
// Kernel 2: W'[n,k] = W[n,k] + SCALE * sum_r loraB[n,r]*loraA[r,k]  -> f16.
// ---------------------------------------------------------------------------
__global__ __launch_bounds__(256) void prep_w_kernel(const float* __restrict__ W,
                                                     const float* __restrict__ lA,
                                                     const float* __restrict__ lB,
                                                     _Float16* __restrict__ wp) {
    __shared__ float A_lds[16][256];
    __shared__ float B_lds[256];
    const int t = threadIdx.x;
    const int n0 = blockIdx.x * 16;

    B_lds[t] = lB[(size_t)n0 * 16 + t];

    for (int kc = 0; kc < 16; ++kc) {
        const int k = kc * 256 + t;
        __syncthreads();
#pragma unroll
        for (int r = 0; r < 16; ++r) A_lds[r][t] = lA[(size_t)r * K_DIM + k];
        __syncthreads();
#pragma unroll 4
        for (int row = 0; row < 16; ++row) {
            float acc = W[(size_t)(n0 + row) * K_DIM + k];
            float dot = 0.f;
#pragma unroll
            for (int r = 0; r < 16; ++r) dot += B_lds[row * 16 + r] * A_lds[r][t];
            acc += LORA_SCALE * dot;
            wp[(size_t)(n0 + row) * K_DIM + k] = (_Float16)acc;
        }
    }
}

// ---------------------------------------------------------------------------
// Kernel 3: 256x256-tile GEMM, BK=64, 8 waves (2m x 4n), counted-vmcnt
// double-buffered pipeline, XOR-swizzled LDS, setprio, XCD swizzle.
// C[m,n] = sum_k A[m,k]*B[n,k] + bias[n].
// ---------------------------------------------------------------------------
__device__ __forceinline__ void load_lds16(const void* g, void* l) {
    __builtin_amdgcn_global_load_lds(
        (const __attribute__((address_space(1))) unsigned int*)(uintptr_t)g,
        (__attribute__((address_space(3))) unsigned int*)(uintptr_t)l,
        16, 0, 0);
}

// Phase-edge fence: drain LDS-op queue, pin compute/ds_reads (rule 18 defense).
#define FENCE() do { \
        asm volatile("s_waitcnt lgkmcnt(0)" ::: "memory"); \
        __builtin_amdgcn_sched_barrier(0); \
    } while (0)

__global__ __launch_bounds__(512, 2) void gemm256_kernel(const _Float16* __restrict__ A,
                                                         const _Float16* __restrict__ B,
                                                         const float* __restrict__ bias,
                                                         float* __restrict__ C) {
    // Swizzled layout: tile row r (stride 64 f16 = 128B), k-slot s (8 f16 = 16B):
    //   LDS element = r*64 + ((s ^ (r&7)) * 8)
    // Staging writes are linear (global_load_lds); the global SOURCE col-chunk is
    // pre-swizzled with the same XOR involution, so reads apply s^(r&7) and match.
    __shared__ _Float16 As[2][BM * BK];  // 2 x 32 KiB
    __shared__ _Float16 Bs[2][BN * BK];  // 2 x 32 KiB  -> 128 KiB total

    const int tid  = threadIdx.x;
    const int lane = tid & 63;
    const int wave = tid >> 6;    // 0..7
    const int wm   = wave >> 2;   // 0..1 : m-half of tile (128 rows)
    const int wn   = wave & 3;    // 0..3 : n-quarter of tile (64 cols)
    const int quad = lane >> 4;   // 0..3 : k-slot within 32-k-half
    const int r16  = lane & 15;
    const int swz  = r16 & 7;
    const int cb   = (quad ^ swz) << 3;  // element offset of swizzled slot, h=0

    // XCD-bijective remap: 1024 wgs, 8 XCDs -> 128 contiguous tiles per XCD.
    const int bid = blockIdx.x;
    const int id  = (bid & 7) * (1024 / 8) + (bid >> 3);
    const int tm  = id >> 4;   // 64 m-tiles
    const int tn  = id & 15;   // 16 n-tiles
    const int m0  = tm * BM;
    const int n0  = tn * BN;

    // Staging: per matrix 2048 16B-chunks/tile; 4 per thread (chunk c = l*512+tid).
    // LDS dest chunk c (row=c>>3, u=c&7) holds global col-chunk (u ^ (row&7)).
    const int u8 = tid & 7;
    const _Float16* ga[4];
    const _Float16* gb[4];
    int lof[4];
#pragma unroll
    for (int l = 0; l < 4; ++l) {
        const int c   = l * 512 + tid;
        const int row = c >> 3;
        const int sc  = (u8 ^ (row & 7)) << 3;
        ga[l]  = A + (size_t)(m0 + row) * K_DIM + sc;
        gb[l]  = B + (size_t)(n0 + row) * K_DIM + sc;
        lof[l] = c << 3;
    }

    const int ab = (wm * 128 + r16) * BK;  // A-frag row base (element)
    const int bb = (wn * 64 + r16) * BK;   // B-frag row base

    f32x4 acc[8][4] = {};

#define STAGE(P) do { \
        _Pragma("unroll") \
        for (int l = 0; l < 4; ++l) { load_lds16(ga[l], &As[P][lof[l]]); ga[l] += BK; } \
        _Pragma("unroll") \
        for (int l = 0; l < 4; ++l) { load_lds16(gb[l], &Bs[P][lof[l]]); gb[l] += BK; } \
    } while (0)

#define MFMA_Q(ILO, JLO, BF) \
        __builtin_amdgcn_s_setprio(1); \
        _Pragma("unroll") \
        for (int i = 0; i < 4; ++i) \
            _Pragma("unroll") \
            for (int j = 0; j < 2; ++j) { \
                acc[(ILO) + i][(JLO) + j] = __builtin_amdgcn_mfma_f32_16x16x32_f16( \
                    a[i][0], BF[j][0], acc[(ILO) + i][(JLO) + j], 0, 0, 0); \
                acc[(ILO) + i][(JLO) + j] = __builtin_amdgcn_mfma_f32_16x16x32_f16( \
                    a[i][1], BF[j][1], acc[(ILO) + i][(JLO) + j], 0, 0, 0); \
            } \
        __builtin_amdgcn_s_setprio(0);

    // 4 quadrants per K-tile; B frags held across, A re-read per m-half.
#define COMPUTE(P) do { \
        half8 a[4][2], b0[2][2], b1[2][2]; \
        _Pragma("unroll") \
        for (int i = 0; i < 4; ++i) { \
            a[i][0] = *(const half8*)&As[P][ab + (i * 16) * BK + cb]; \
            a[i][1] = *(const half8*)&As[P][ab + (i * 16) * BK + (cb ^ 32)]; \
        } \
        _Pragma("unroll") \
        for (int j = 0; j < 2; ++j) { \
            b0[j][0] = *(const half8*)&Bs[P][bb + (j * 16) * BK + cb]; \
            b0[j][1] = *(const half8*)&Bs[P][bb + (j * 16) * BK + (cb ^ 32)]; \
        } \
        MFMA_Q(0, 0, b0) \
        _Pragma("unroll") \
        for (int j = 0; j < 2; ++j) { \
            b1[j][0] = *(const half8*)&Bs[P][bb + ((j + 2) * 16) * BK + cb]; \
            b1[j][1] = *(const half8*)&Bs[P][bb + ((j + 2) * 16) * BK + (cb ^ 32)]; \
        } \
        MFMA_Q(0, 2, b1) \
        _Pragma("unroll") \
        for (int i = 0; i < 4; ++i) { \
            a[i][0] = *(const half8*)&As[P][ab + ((i + 4) * 16) * BK + cb]; \
            a[i][1] = *(const half8*)&As[P][ab + ((i + 4) * 16) * BK + (cb ^ 32)]; \
        } \
        MFMA_Q(4, 0, b0) \
        MFMA_Q(4, 2, b1) \
    } while (0)

    // Prologue: stage tiles 0 and 1; wait tile 0 only (counted).
    STAGE(0);
    STAGE(1);
    asm volatile("s_waitcnt vmcnt(8)" ::: "memory");
    __builtin_amdgcn_s_barrier();

#pragma unroll 1
    for (int it = 0; it < NT / 2 - 1; ++it) {  // 31 iterations, 2 K-tiles each
        COMPUTE(0);                            // tile 2it from buf0
        FENCE();                               // reads retired before overwrite
        __builtin_amdgcn_s_barrier();          // all waves done reading buf0
        STAGE(0);                              // tile 2it+2 -> buf0
        asm volatile("s_waitcnt vmcnt(8)" ::: "memory");  // tile 2it+1 landed
        __builtin_amdgcn_s_barrier();          // cross-wave visibility
        COMPUTE(1);                            // tile 2it+1 from buf1
        FENCE();
        __builtin_amdgcn_s_barrier();
        STAGE(1);                              // tile 2it+3 -> buf1
        asm volatile("s_waitcnt vmcnt(8)" ::: "memory");  // tile 2it+2 landed
        __builtin_amdgcn_s_barrier();
    }
    // Tail: tiles 62, 63 (already staged).
    COMPUTE(0);
    FENCE();
    asm volatile("s_waitcnt vmcnt(0)" ::: "memory");  // tile 63 landed (drain ok in tail)
    __builtin_amdgcn_s_barrier();
    COMPUTE(1);

#undef COMPUTE
#undef MFMA_Q
#undef STAGE

    // Epilogue: C/D layout col = lane&15 (n), row = quad*4 + reg (m).
#pragma unroll
    for (int j = 0; j < 4; ++j) {
        const int n = n0 + wn * 64 + j * 16 + r16;
        const float bv = bias[n];
#pragma unroll
        for (int i = 0; i < 8; ++i) {
            const int mbase = m0 + wm * 128 + i * 16 + quad * 4;
#pragma unroll
            for (int r = 0; r < 4; ++r) {
                C[(size_t)(mbase + r) * N_DIM + n] = acc[i][j][r] + bv;
            }
        }
    }
}

// ---------------------------------------------------------------------------
extern "C" void kernel_launch(void* const* d_in, const int* in_sizes, int n_in,
                              void* d_out, int out_size, void* d_ws, size_t ws_size,
                              hipStream_t stream) {
    const float* x      = (const float*)d_in[0];  // [4,4096,4096] fp32 -> [M,K]
    const float* weight = (const float*)d_in[1];  // [N,K] fp32
    const float* bias   = (const float*)d_in[2];  // [N] fp32
    const float* lora_A = (const float*)d_in[3];  // [16,K] fp32
    const float* lora_B = (const float*)d_in[4];  // [N,16] fp32
    float* out = (float*)d_out;

    _Float16* xb = (_Float16*)d_ws;                                       // 128 MiB
    _Float16* wp = (_Float16*)((char*)d_ws + (size_t)M_DIM * K_DIM * 2);  // +32 MiB

    // 1) x -> f16
    cvt_x_kernel<<<dim3((M_DIM * (size_t)K_DIM) / (256 * 8)), dim3(256), 0, stream>>>(x, xb);
    // 2) W' = W + loraB@loraA -> f16
    prep_w_kernel<<<dim3(N_DIM / 16), dim3(256), 0, stream>>>(weight, lora_A, lora_B, wp);
    // 3) GEMM + bias (256x256 tiles, 1024 wgs)
    gemm256_kernel<<<dim3((M_DIM / BM) * (N_DIM / BN)), dim3(512), 0, stream>>>(xb, wp, bias, out);
}

// Round 3
// 941.703 us; speedup vs baseline: 1.2182x; 1.0932x over previous
//
#include <hip/hip_runtime.h>
#include <stdint.h>

// out[M,N] = x[M,K] @ W'[N,K]^T + bias[N], W' = W + SCALE*(loraB @ loraA)
// M = 16384 (B*S), N = 4096, K = 4096. SCALE = 16/16 = 1.0.
#define M_DIM 16384
#define N_DIM 4096
#define K_DIM 4096
#define LORA_SCALE 1.0f

#define BM 256
#define BN 256
#define BK 64
#define NT (K_DIM / BK)  // 64 K-tiles

typedef _Float16 half8 __attribute__((ext_vector_type(8)));
typedef float f32x4 __attribute__((ext_vector_type(4)));

// ---------------------------------------------------------------------------
// Kernel 1 (fused prep): blocks [0,256) compute W' = W + loraB@loraA -> f16
// (latency-bound, starts first); blocks [256, 33024) convert x fp32 -> f16
// (BW-bound, hides the W-prep underneath).
// ---------------------------------------------------------------------------
__global__ __launch_bounds__(256) void prep_kernel(const float* __restrict__ x,
                                                   _Float16* __restrict__ xb,
                                                   const float* __restrict__ W,
                                                   const float* __restrict__ lA,
                                                   const float* __restrict__ lB,
                                                   _Float16* __restrict__ wp) {
    __shared__ float A_lds[16][256];
    __shared__ float B_lds[256];
    const int t = threadIdx.x;

    if (blockIdx.x < 256) {
        const int n0 = blockIdx.x * 16;
        B_lds[t] = lB[(size_t)n0 * 16 + t];
        for (int kc = 0; kc < 16; ++kc) {
            const int k = kc * 256 + t;
            __syncthreads();
#pragma unroll
            for (int r = 0; r < 16; ++r) A_lds[r][t] = lA[(size_t)r * K_DIM + k];
            __syncthreads();
#pragma unroll 4
            for (int row = 0; row < 16; ++row) {
                float acc = W[(size_t)(n0 + row) * K_DIM + k];
                float dot = 0.f;
#pragma unroll
                for (int r = 0; r < 16; ++r) dot += B_lds[row * 16 + r] * A_lds[r][t];
                acc += LORA_SCALE * dot;
                wp[(size_t)(n0 + row) * K_DIM + k] = (_Float16)acc;
            }
        }
        return;
    }

    const size_t base = ((size_t)(blockIdx.x - 256) * 256 + t) * 8;
    f32x4 a = *(const f32x4*)(x + base);
    f32x4 b = *(const f32x4*)(x + base + 4);
    half8 h;
    h[0] = (_Float16)a[0]; h[1] = (_Float16)a[1];
    h[2] = (_Float16)a[2]; h[3] = (_Float16)a[3];
    h[4] = (_Float16)b[0]; h[5] = (_Float16)b[1];
    h[6] = (_Float16)b[2]; h[7] = (_Float16)b[3];
    *(half8*)(xb + base) = h;
}

// ---------------------------------------------------------------------------
// Kernel 2: 256x256 GEMM, BK=64, 8 waves (2m x 4n), 8-phase schedule:
// per K-tile 4 sub-phases {ds_read subtile + issue 1 half-tile -> barrier ->
// lgkmcnt(0) -> 16 MFMA -> barrier}, half-tile ring (8 LDS slots), staging
// 3 half-tiles ahead, vmcnt(6) once per K-tile. C[m,n]=sum_k A[m,k]*B[n,k]+bias.
// ---------------------------------------------------------------------------
__device__ __forceinline__ void load_lds16(const void* g, void* l) {
    __builtin_amdgcn_global_load_lds(
        (const __attribute__((address_space(1))) unsigned int*)(uintptr_t)g,
        (__attribute__((address_space(3))) unsigned int*)(uintptr_t)l,
        16, 0, 0);
}

__global__ __launch_bounds__(512, 2) void gemm256_kernel(const _Float16* __restrict__ A,
                                                         const _Float16* __restrict__ B,
                                                         const float* __restrict__ bias,
                                                         float* __restrict__ C) {
    // Half-tile slots: [dbuf][khalf][256 rows][32 cols f16]. Read swizzle:
    // k-slot' = quad ^ ((row>>1)&3); staging pre-swizzles the global source
    // column with the same involution so gload_lds stays linear (rule 21).
    __shared__ _Float16 As[2][2][256 * 32];  // 4 x 16 KiB
    __shared__ _Float16 Bs[2][2][256 * 32];  // 4 x 16 KiB -> 128 KiB total

    const int tid  = threadIdx.x;
    const int lane = tid & 63;
    const int wave = tid >> 6;    // 0..7
    const int wm   = wave >> 2;   // 0..1 : m-half (128 rows)
    const int wn   = wave & 3;    // 0..3 : n-quarter (64 cols)
    const int quad = lane >> 4;   // 0..3 : k-chunk within 32-k half
    const int r16  = lane & 15;
    const int swz  = (quad ^ ((r16 >> 1) & 3)) << 3;  // swizzled k-chunk (elements)

    // XCD-bijective remap: 1024 wgs, 8 XCDs -> 128 contiguous tiles per XCD.
    const int bid = blockIdx.x;
    const int id  = (bid & 7) * 128 + (bid >> 3);
    const int m0  = (id >> 4) * BM;
    const int n0  = (id & 15) * BN;

    // Staging: half-tile = 16 KiB = 2 wave-loads/wave. Thread handles chunks
    // c = tid and c = tid+512; chunk c -> row c>>2, LDS k-slot c&3, global
    // k-chunk (c&3) ^ ((c>>3)&3) (inverse swizzle).
    const int  srow = tid >> 2;
    const int  scol = (((tid & 3) ^ ((tid >> 3) & 3)) << 3);
    const _Float16* gA = A + (size_t)(m0 + srow) * K_DIM + scol;
    const _Float16* gB = B + (size_t)(n0 + srow) * K_DIM + scol;
    const int ldst0 = tid * 8;
    const int ldst1 = (tid + 512) * 8;

    // Fragment read bases (elements within one [256*32] slot).
    const int arow = (wm * 128 + r16) * 32 + swz;
    const int brow = (wn * 64 + r16) * 32 + swz;

    f32x4 acc[8][4] = {};
    half8 a[8], b0, b1;

#define ISSUE_A(DB, KH, T) do { \
        const _Float16* g_ = gA + (size_t)((T) * 64 + (KH) * 32); \
        load_lds16(g_, &As[DB][KH][ldst0]); \
        load_lds16(g_ + (size_t)128 * K_DIM, &As[DB][KH][ldst1]); \
    } while (0)
#define ISSUE_B(DB, KH, T) do { \
        const _Float16* g_ = gB + (size_t)((T) * 64 + (KH) * 32); \
        load_lds16(g_, &Bs[DB][KH][ldst0]); \
        load_lds16(g_ + (size_t)128 * K_DIM, &Bs[DB][KH][ldst1]); \
    } while (0)

#define MID() do { \
        asm volatile("" ::: "memory"); __builtin_amdgcn_sched_barrier(0); \
        __builtin_amdgcn_s_barrier(); \
        asm volatile("s_waitcnt lgkmcnt(0)" ::: "memory"); \
        __builtin_amdgcn_sched_barrier(0); \
        __builtin_amdgcn_s_setprio(1); \
    } while (0)
#define ENDP() do { \
        __builtin_amdgcn_s_setprio(0); \
        asm volatile("" ::: "memory"); __builtin_amdgcn_sched_barrier(0); \
        __builtin_amdgcn_s_barrier(); \
    } while (0)

#define MFMA16(JLO) \
        _Pragma("unroll") \
        for (int i_ = 0; i_ < 8; ++i_) { \
            acc[i_][JLO]       = __builtin_amdgcn_mfma_f32_16x16x32_f16(a[i_], b0, acc[i_][JLO], 0, 0, 0); \
            acc[i_][(JLO) + 1] = __builtin_amdgcn_mfma_f32_16x16x32_f16(a[i_], b1, acc[i_][(JLO) + 1], 0, 0, 0); \
        }

// Phase with A-frag reload (p0/p2): 8 A reads + 2 B reads, 16 MFMA.
#define PH_A(DB, KH, JLO, ISS) do { \
        _Pragma("unroll") \
        for (int i_ = 0; i_ < 8; ++i_) a[i_] = *(const half8*)&As[DB][KH][arow + i_ * 512]; \
        b0 = *(const half8*)&Bs[DB][KH][brow + (JLO) * 512]; \
        b1 = *(const half8*)&Bs[DB][KH][brow + ((JLO) + 1) * 512]; \
        ISS; MID(); MFMA16(JLO) ENDP(); \
    } while (0)
// Phase reusing A-frags (p1): 2 B reads, 16 MFMA.
#define PH_B(DB, KH, JLO, ISS) do { \
        b0 = *(const half8*)&Bs[DB][KH][brow + (JLO) * 512]; \
        b1 = *(const half8*)&Bs[DB][KH][brow + ((JLO) + 1) * 512]; \
        ISS; MID(); MFMA16(JLO) ENDP(); \
    } while (0)
// p3: no trailing barrier (tile-end sequence follows).
#define PH_B3(DB, KH, JLO, ISS) do { \
        b0 = *(const half8*)&Bs[DB][KH][brow + (JLO) * 512]; \
        b1 = *(const half8*)&Bs[DB][KH][brow + ((JLO) + 1) * 512]; \
        ISS; MID(); MFMA16(JLO) \
    } while (0)

// Tile t (buffer DB): issues stream s=4t+7..4t+10 at phases p0..p3.
// p0 overwrites Bs[!DB][1] (last read 2 tiles ago); p1 As[DB][0] (read p0);
// p2 Bs[DB][0] (read p0,p1); p3 As[DB][1] (read p2). All closed by barriers.
#define TILE(DB, T1, T2) do { \
        PH_A(DB, 0, 0, ISSUE_B(1 - (DB), 1, T1)); \
        PH_B(DB, 0, 2, ISSUE_A(DB, 0, T2)); \
        PH_A(DB, 1, 0, ISSUE_B(DB, 0, T2)); \
        PH_B3(DB, 1, 2, ISSUE_A(DB, 1, T2)); \
    } while (0)
#define ENDT6() do { \
        __builtin_amdgcn_s_setprio(0); \
        asm volatile("" ::: "memory"); __builtin_amdgcn_sched_barrier(0); \
        asm volatile("s_waitcnt vmcnt(6)" ::: "memory"); \
        __builtin_amdgcn_s_barrier(); \
    } while (0)

    // Prologue: stream s=0..6 (tile 0 complete + 3 half-tiles of tile 1).
    ISSUE_A(0, 0, 0); ISSUE_B(0, 0, 0); ISSUE_A(0, 1, 0); ISSUE_B(0, 1, 0);
    ISSUE_A(1, 0, 1); ISSUE_B(1, 0, 1); ISSUE_A(1, 1, 1);
    asm volatile("s_waitcnt vmcnt(6)" ::: "memory");  // tile 0 landed, 3 ht in flight
    __builtin_amdgcn_s_barrier();

#pragma unroll 1
    for (int ip = 0; ip < 31; ++ip) {  // tiles 0..61
        const int t1 = 2 * ip + 1, t2 = 2 * ip + 2, t3 = 2 * ip + 3;
        TILE(0, t1, t2);
        ENDT6();
        TILE(1, t2, t3);
        ENDT6();
    }
    // Tile 62: only s=255 (tile 63 B-k1) remains to issue; then full drain.
    PH_A(0, 0, 0, ISSUE_B(1, 1, 63));
    PH_B(0, 0, 2, (void)0);
    PH_A(0, 1, 0, (void)0);
    PH_B3(0, 1, 2, (void)0);
    __builtin_amdgcn_s_setprio(0);
    asm volatile("" ::: "memory"); __builtin_amdgcn_sched_barrier(0);
    asm volatile("s_waitcnt vmcnt(0)" ::: "memory");  // tile 63 fully landed
    __builtin_amdgcn_s_barrier();
    // Tile 63: no issues.
    PH_A(1, 0, 0, (void)0);
    PH_B(1, 0, 2, (void)0);
    PH_A(1, 1, 0, (void)0);
    PH_B3(1, 1, 2, (void)0);
    __builtin_amdgcn_s_setprio(0);

#undef TILE
#undef ENDT6
#undef PH_A
#undef PH_B
#undef PH_B3
#undef MFMA16
#undef MID
#undef ENDP
#undef ISSUE_A
#undef ISSUE_B

    // Epilogue: C/D layout col = lane&15 (n), row = quad*4 + reg (m).
#pragma unroll
    for (int j = 0; j < 4; ++j) {
        const int n = n0 + wn * 64 + j * 16 + r16;
        const float bv = bias[n];
#pragma unroll
        for (int i = 0; i < 8; ++i) {
            const int mbase = m0 + wm * 128 + i * 16 + quad * 4;
#pragma unroll
            for (int r = 0; r < 4; ++r) {
                C[(size_t)(mbase + r) * N_DIM + n] = acc[i][j][r] + bv;
            }
        }
    }
}

// ---------------------------------------------------------------------------
extern "C" void kernel_launch(void* const* d_in, const int* in_sizes, int n_in,
                              void* d_out, int out_size, void* d_ws, size_t ws_size,
                              hipStream_t stream) {
    const float* x      = (const float*)d_in[0];  // [4,4096,4096] fp32 -> [M,K]
    const float* weight = (const float*)d_in[1];  // [N,K] fp32
    const float* bias   = (const float*)d_in[2];  // [N] fp32
    const float* lora_A = (const float*)d_in[3];  // [16,K] fp32
    const float* lora_B = (const float*)d_in[4];  // [N,16] fp32
    float* out = (float*)d_out;

    _Float16* xb = (_Float16*)d_ws;                                       // 128 MiB
    _Float16* wp = (_Float16*)((char*)d_ws + (size_t)M_DIM * K_DIM * 2);  // +32 MiB

    // 1) fused: W' prep (256 blocks, first) + x->f16 (32768 blocks)
    prep_kernel<<<dim3(256 + (M_DIM * (size_t)K_DIM) / (256 * 8)), dim3(256), 0, stream>>>(
        x, xb, weight, lora_A, lora_B, wp);
    // 2) GEMM + bias (256x256 tiles, 1024 wgs)
    gemm256_kernel<<<dim3((M_DIM / BM) * (N_DIM / BN)), dim3(512), 0, stream>>>(xb, wp, bias, out);
}